// Round 2
// baseline (517.108 us; speedup 1.0000x reference)
//
#include <hip/hip_runtime.h>
#include <hip/hip_bf16.h>

typedef unsigned short u16;
typedef __attribute__((ext_vector_type(8))) short short8;
typedef __attribute__((ext_vector_type(4))) float f32x4;

constexpr int SEQ = 2048;
constexpr int NH  = 16;
constexpr int HD  = 64;
constexpr float SCALE = 0.125f;   // 1/sqrt(64)

// LDS pitches (elements) -- padded to stagger banks, rows 16B-aligned
constexpr int KP = 72;   // K tile [32][KP] bf16
constexpr int VP = 40;   // V transposed [64][VP] bf16  (Vt[d][kj])
constexpr int PP = 40;   // P tile per wave [16][PP] bf16

__device__ __forceinline__ f32x4 mfma16(short8 a, short8 b, f32x4 c) {
    return __builtin_amdgcn_mfma_f32_16x16x32_bf16(a, b, c, 0, 0, 0);
}

__device__ __forceinline__ u16 bf16r(float x) {
    __hip_bfloat16 h = __float2bfloat16(x);
    return *reinterpret_cast<u16*>(&h);
}

// load 8 contiguous fp32, round to bf16, pack as short8
__device__ __forceinline__ short8 cv8(const float* p) {
    float4 a = *(const float4*)p;
    float4 b = *(const float4*)(p + 4);
    short8 r;
    r[0] = (short)bf16r(a.x); r[1] = (short)bf16r(a.y);
    r[2] = (short)bf16r(a.z); r[3] = (short)bf16r(a.w);
    r[4] = (short)bf16r(b.x); r[5] = (short)bf16r(b.y);
    r[6] = (short)bf16r(b.z); r[7] = (short)bf16r(b.w);
    return r;
}

__global__ __launch_bounds__(256, 4)
void attn_fwd_kernel(const float* __restrict__ qkv, float* __restrict__ out) {
    __shared__ u16 Ks[32 * KP];
    __shared__ u16 Vt[64 * VP];
    __shared__ u16 Ps[4][16 * PP];

    // block order: bh*32 + qt  (interleaves causal trip counts across CUs)
    const int qt = blockIdx.x & 31;          // 32 q-tiles of 64 rows
    const int bh = blockIdx.x >> 5;
    const int b  = bh >> 4;
    const int h  = bh & 15;

    const int tid  = threadIdx.x;
    const int wave = tid >> 6;
    const int lane = tid & 63;
    const int llo  = lane & 15;
    const int lhi  = lane >> 4;              // 0..3

    const int q0b = qt * 64;                 // block's first q row
    const int q0  = q0b + wave * 16;         // wave's first q row

    // element offset for (s, c, d): basebh + s*3072 + c*1024 + d   (c in {0,1,2})
    const size_t basebh = (size_t)b * SEQ * 3072 + (size_t)h * HD;

    // ---- Q fragments (bf16), held in registers for the whole kernel ----
    // A-frag (16x32): lane holds A[lane&15][(lane>>4)*8 + j], j=0..7
    short8 qf[2];
    {
        const float* qp = qkv + basebh + (size_t)(q0 + llo) * 3072 + lhi * 8;
        qf[0] = cv8(qp);                     // d =      lhi*8 .. +7
        qf[1] = cv8(qp + 32);                // d = 32 + lhi*8 .. +7
    }

    f32x4 acc[4] = {};                       // O accum: 4 d-chunks of 16 cols
    float m_r[4], l_r[4];
#pragma unroll
    for (int r = 0; r < 4; ++r) { m_r[r] = -INFINITY; l_r[r] = 0.f; }

    const int ntiles = 2 * qt + 2;           // K tiles of 32 rows, up to q0b+63
    for (int kt = 0; kt < ntiles; ++kt) {
        const int kbase = kt * 32;
        __syncthreads();                     // protect LDS reuse across iterations
        {
            // cooperative stage: 256 threads; each converts 8 K-floats + 8 V-floats
            const int r  = tid >> 3;         // 0..31 (k row)
            const int c8 = (tid & 7) * 8;    // 0..56 (d)
            const float* kp = qkv + basebh + (size_t)(kbase + r) * 3072 + 1024 + c8;
            *(short8*)(&Ks[r * KP + c8]) = cv8(kp);
            const float* vp = qkv + basebh + (size_t)(kbase + r) * 3072 + 2048 + c8;
            float4 v0 = *(const float4*)vp;
            float4 v1 = *(const float4*)(vp + 4);
            Vt[(c8 + 0) * VP + r] = bf16r(v0.x);
            Vt[(c8 + 1) * VP + r] = bf16r(v0.y);
            Vt[(c8 + 2) * VP + r] = bf16r(v0.z);
            Vt[(c8 + 3) * VP + r] = bf16r(v0.w);
            Vt[(c8 + 4) * VP + r] = bf16r(v1.x);
            Vt[(c8 + 5) * VP + r] = bf16r(v1.y);
            Vt[(c8 + 6) * VP + r] = bf16r(v1.z);
            Vt[(c8 + 7) * VP + r] = bf16r(v1.w);
        }
        __syncthreads();

        if (kbase > q0 + 15) continue;       // fully masked for this wave (barriers already hit)

        // ---- QK^T: two 16-col groups ----
        float p[2][4];
        float pmax[4];
#pragma unroll
        for (int r = 0; r < 4; ++r) pmax[r] = -INFINITY;
#pragma unroll
        for (int cg = 0; cg < 2; ++cg) {
            // B-frag (K^T 32x16 slice): lane holds K[cg*16 + (lane&15)][(lane>>4)*8 + j]
            const u16* kb = &Ks[(cg * 16 + llo) * KP + lhi * 8];
            short8 kf0 = *(const short8*)(kb);
            short8 kf1 = *(const short8*)(kb + 32);
            f32x4 s = {0.f, 0.f, 0.f, 0.f};
            s = mfma16(qf[0], kf0, s);
            s = mfma16(qf[1], kf1, s);
            const int kj = kbase + cg * 16 + llo;
#pragma unroll
            for (int r = 0; r < 4; ++r) {
                const int qi = q0 + lhi * 4 + r;    // C/D: row=(lane>>4)*4+r, col=lane&15
                float sv = s[r] * SCALE;
                if (kj > qi) sv = -INFINITY;        // causal mask
                p[cg][r] = sv;
                pmax[r] = fmaxf(pmax[r], sv);
            }
        }
        // row-max across the 16 col-lanes (lanes sharing lane>>4)
#pragma unroll
        for (int off = 1; off < 16; off <<= 1)
#pragma unroll
            for (int r = 0; r < 4; ++r)
                pmax[r] = fmaxf(pmax[r], __shfl_xor(pmax[r], off, 64));

        float alpha[4], psum[4];
#pragma unroll
        for (int r = 0; r < 4; ++r) {
            float mn = fmaxf(m_r[r], pmax[r]);
            alpha[r] = __expf(m_r[r] - mn);         // first tile: exp(-inf - finite) = 0
            m_r[r] = mn;
            float p0 = __expf(p[0][r] - mn);
            float p1 = __expf(p[1][r] - mn);
            p[0][r] = p0; p[1][r] = p1;
            psum[r] = p0 + p1;
        }
#pragma unroll
        for (int off = 1; off < 16; off <<= 1)
#pragma unroll
            for (int r = 0; r < 4; ++r)
                psum[r] += __shfl_xor(psum[r], off, 64);
#pragma unroll
        for (int r = 0; r < 4; ++r) l_r[r] = l_r[r] * alpha[r] + psum[r];

        // rescale O (same row mapping as S)
#pragma unroll
        for (int dc = 0; dc < 4; ++dc)
#pragma unroll
            for (int r = 0; r < 4; ++r)
                acc[dc][r] *= alpha[r];

        // ---- P -> bf16 A-frag via per-wave LDS tile ----
        u16* pw = Ps[wave];
#pragma unroll
        for (int cg = 0; cg < 2; ++cg)
#pragma unroll
            for (int r = 0; r < 4; ++r)
                pw[(lhi * 4 + r) * PP + cg * 16 + llo] = bf16r(p[cg][r]);
        short8 pf = *(const short8*)(&pw[llo * PP + lhi * 8]);

        // ---- PV: O[dc] += P * V ----
        // B-frag: lane needs V[(lane>>4)*8 + j][dc*16 + (lane&15)] -> contiguous in Vt
#pragma unroll
        for (int dc = 0; dc < 4; ++dc) {
            short8 vf = *(const short8*)(&Vt[(dc * 16 + llo) * VP + lhi * 8]);
            acc[dc] = mfma16(pf, vf, acc[dc]);
        }
    }

    // ---- epilogue: divide by l, write fp32 ----
#pragma unroll
    for (int dc = 0; dc < 4; ++dc)
#pragma unroll
        for (int r = 0; r < 4; ++r) {
            const int qi = q0 + lhi * 4 + r;
            const int d  = dc * 16 + llo;
            out[((size_t)b * SEQ + qi) * (NH * HD) + h * HD + d] = acc[dc][r] / l_r[r];
        }
}

extern "C" void kernel_launch(void* const* d_in, const int* in_sizes, int n_in,
                              void* d_out, int out_size, void* d_ws, size_t ws_size,
                              hipStream_t stream) {
    const float* qkv = (const float*)d_in[0];
    float* out = (float*)d_out;
    const int B = in_sizes[0] / (SEQ * 3 * NH * HD);   // = 4
    dim3 grid(B * NH * (SEQ / 64));                    // 2048 blocks
    dim3 block(256);
    attn_fwd_kernel<<<grid, block, 0, stream>>>(qkv, out);
}

// Round 3
// 285.286 us; speedup vs baseline: 1.8126x; 1.8126x over previous
//
#include <hip/hip_runtime.h>
#include <hip/hip_bf16.h>

typedef unsigned short u16;
typedef __attribute__((ext_vector_type(8))) short short8;
typedef __attribute__((ext_vector_type(4))) float f32x4;

constexpr int SEQ = 2048;
constexpr int NH  = 16;
constexpr int HD  = 64;
constexpr float SCALE = 0.125f;   // 1/sqrt(64)

constexpr int KP = 72;   // K tile [64][KP] bf16 (144B pitch -> 2-way-free reads)
constexpr int PP = 72;   // P tile per wave [16][PP] bf16
// Vt: [64 d][64 k] bf16, 128B pitch, granule-XOR swizzled by (d&7)

__device__ __forceinline__ f32x4 mfma16(short8 a, short8 b, f32x4 c) {
    return __builtin_amdgcn_mfma_f32_16x16x32_bf16(a, b, c, 0, 0, 0);
}

__device__ __forceinline__ u16 bf16r(float x) {
    __hip_bfloat16 h = __float2bfloat16(x);
    return *reinterpret_cast<u16*>(&h);
}

// load 8 contiguous fp32, round to bf16, pack as short8
__device__ __forceinline__ short8 cv8(const float* p) {
    float4 a = *(const float4*)p;
    float4 b = *(const float4*)(p + 4);
    short8 r;
    r[0] = (short)bf16r(a.x); r[1] = (short)bf16r(a.y);
    r[2] = (short)bf16r(a.z); r[3] = (short)bf16r(a.w);
    r[4] = (short)bf16r(b.x); r[5] = (short)bf16r(b.y);
    r[6] = (short)bf16r(b.z); r[7] = (short)bf16r(b.w);
    return r;
}

__global__ __launch_bounds__(256, 4)
void attn_fwd_kernel(const float* __restrict__ qkv, float* __restrict__ out) {
    __shared__ u16 Ks[64 * KP];
    __shared__ u16 Vt[64 * 64];
    __shared__ u16 Ps[4][16 * PP];

    // XCD-aware swizzle: blocks of the same 8 bh stay on one XCD (blockIdx%8 = XCD).
    const int orig = blockIdx.x;                 // nwg = 1024, 1024%8==0 -> bijective
    const int v    = (orig & 7) * 128 + (orig >> 3);
    const int bh   = v >> 4;
    const int p    = v & 15;                     // pair id: q-tiles {p, 31-p}
    const int b    = bh >> 4;
    const int h    = bh & 15;
    const int qtT[2] = {p, 31 - p};

    const int tid  = threadIdx.x;
    const int wave = tid >> 6;
    const int lane = tid & 63;
    const int llo  = lane & 15;
    const int lhi  = lane >> 4;                  // 0..3

    const int q0[2] = {qtT[0] * 64 + wave * 16, qtT[1] * 64 + wave * 16};

    // element offset for (s, c, d): basebh + s*3072 + c*1024 + d
    const size_t basebh = (size_t)b * SEQ * 3072 + (size_t)h * HD;

    // ---- Q fragments (bf16) for both q-tiles, in registers all kernel ----
    short8 qf[2][2];
#pragma unroll
    for (int t = 0; t < 2; ++t) {
        const float* qp = qkv + basebh + (size_t)(q0[t] + llo) * 3072 + lhi * 8;
        qf[t][0] = cv8(qp);
        qf[t][1] = cv8(qp + 32);
    }

    f32x4 acc[2][4] = {};
    float m_r[2][4], l_r[2][4];
#pragma unroll
    for (int t = 0; t < 2; ++t)
#pragma unroll
        for (int r = 0; r < 4; ++r) { m_r[t][r] = -INFINITY; l_r[t][r] = 0.f; }

    const int NT = 32 - p;                       // k-tiles of 64 rows (covers both q-tiles)
    for (int kt = 0; kt < NT; ++kt) {
        const int kbase = kt * 64;
        __syncthreads();
        // ---- stage K rows (coalesced: 4 lanes cover one 256B row) ----
        {
            const int r   = tid >> 2;            // 0..63
            const int c16 = (tid & 3) * 16;      // 0..48
            const float* kp = qkv + basebh + (size_t)(kbase + r) * 3072 + 1024 + c16;
            *(short8*)(&Ks[r * KP + c16])     = cv8(kp);
            *(short8*)(&Ks[r * KP + c16 + 8]) = cv8(kp + 8);
        }
        // ---- stage V transposed: lane owns column d; coalesced 256B per row-read ----
        {
            const int d  = tid & 63;
            const int rg = tid >> 6;             // 16-row group
            const float* vp = qkv + basebh + (size_t)(kbase + rg * 16) * 3072 + 2048 + d;
#pragma unroll
            for (int g = 0; g < 2; ++g) {        // two 8-row halves -> two b128 writes
                short8 pk;
#pragma unroll
                for (int j = 0; j < 8; ++j)
                    pk[j] = (short)bf16r(vp[(g * 8 + j) * 3072]);
                char* dst = (char*)Vt + d * 128 + ((rg * 32 + g * 16) ^ ((d & 7) << 4));
                *(short8*)dst = pk;
            }
        }
        __syncthreads();

#pragma unroll
        for (int t = 0; t < 2; ++t) {
            if (kbase > q0[t] + 15) continue;    // tile fully masked / out of range

            // ---- QK^T: four 16-col groups over 64 k ----
            float pv4[4][4];
            float pmax[4];
#pragma unroll
            for (int r = 0; r < 4; ++r) pmax[r] = -INFINITY;
#pragma unroll
            for (int cg = 0; cg < 4; ++cg) {
                const u16* kb = &Ks[(cg * 16 + llo) * KP + lhi * 8];
                short8 kf0 = *(const short8*)(kb);
                short8 kf1 = *(const short8*)(kb + 32);
                f32x4 s = {0.f, 0.f, 0.f, 0.f};
                s = mfma16(qf[t][0], kf0, s);
                s = mfma16(qf[t][1], kf1, s);
                const int kj = kbase + cg * 16 + llo;
#pragma unroll
                for (int r = 0; r < 4; ++r) {
                    const int qi = q0[t] + lhi * 4 + r;   // C/D: row=(lane>>4)*4+r, col=lane&15
                    float sv = s[r] * SCALE;
                    sv = (kj > qi) ? -INFINITY : sv;
                    pv4[cg][r] = sv;
                    pmax[r] = fmaxf(pmax[r], sv);
                }
            }
#pragma unroll
            for (int off = 1; off < 16; off <<= 1)
#pragma unroll
                for (int r = 0; r < 4; ++r)
                    pmax[r] = fmaxf(pmax[r], __shfl_xor(pmax[r], off, 64));

            float alpha[4], psum[4];
#pragma unroll
            for (int r = 0; r < 4; ++r) {
                float mn = fmaxf(m_r[t][r], pmax[r]);
                alpha[r] = __expf(m_r[t][r] - mn);
                m_r[t][r] = mn;
                float s0 = 0.f;
#pragma unroll
                for (int cg = 0; cg < 4; ++cg) {
                    pv4[cg][r] = __expf(pv4[cg][r] - mn);
                    s0 += pv4[cg][r];
                }
                psum[r] = s0;
            }
#pragma unroll
            for (int off = 1; off < 16; off <<= 1)
#pragma unroll
                for (int r = 0; r < 4; ++r)
                    psum[r] += __shfl_xor(psum[r], off, 64);
#pragma unroll
            for (int r = 0; r < 4; ++r) l_r[t][r] = l_r[t][r] * alpha[r] + psum[r];
#pragma unroll
            for (int dc = 0; dc < 4; ++dc)
#pragma unroll
                for (int r = 0; r < 4; ++r)
                    acc[t][dc][r] *= alpha[r];

            // ---- P -> bf16 A-frag via per-wave LDS tile (wave-local, no barrier) ----
            u16* pw = Ps[wave];
#pragma unroll
            for (int cg = 0; cg < 4; ++cg)
#pragma unroll
                for (int r = 0; r < 4; ++r)
                    pw[(lhi * 4 + r) * PP + cg * 16 + llo] = bf16r(pv4[cg][r]);

            // ---- PV: two k-slices of 32 ----
#pragma unroll
            for (int ks = 0; ks < 2; ++ks) {
                short8 pf = *(const short8*)(&pw[llo * PP + ks * 32 + lhi * 8]);
#pragma unroll
                for (int dc = 0; dc < 4; ++dc) {
                    const char* vsrc = (const char*)Vt + (dc * 16 + llo) * 128 +
                                       ((ks * 64 + lhi * 16) ^ ((llo & 7) << 4));
                    short8 vf = *(const short8*)vsrc;
                    acc[t][dc] = mfma16(pf, vf, acc[t][dc]);
                }
            }
        }
    }

    // ---- epilogue: divide by l, write fp32 ----
#pragma unroll
    for (int t = 0; t < 2; ++t)
#pragma unroll
        for (int dc = 0; dc < 4; ++dc)
#pragma unroll
            for (int r = 0; r < 4; ++r) {
                const int qi = q0[t] + lhi * 4 + r;
                const int d  = dc * 16 + llo;
                out[((size_t)b * SEQ + qi) * (NH * HD) + h * HD + d] = acc[t][dc][r] / l_r[t][r];
            }
}

extern "C" void kernel_launch(void* const* d_in, const int* in_sizes, int n_in,
                              void* d_out, int out_size, void* d_ws, size_t ws_size,
                              hipStream_t stream) {
    const float* qkv = (const float*)d_in[0];
    float* out = (float*)d_out;
    const int B = in_sizes[0] / (SEQ * 3 * NH * HD);   // = 4
    dim3 grid(B * NH * 16);                            // 1024 blocks (16 q-tile pairs)
    dim3 block(256);
    attn_fwd_kernel<<<grid, block, 0, stream>>>(qkv, out);
}